// Round 3
// baseline (723.231 us; speedup 1.0000x reference)
//
#include <hip/hip_runtime.h>
#include <hip/hip_bf16.h>

#define H2 16
#define HKV 8
#define DHEAD 128
#define HID 1024
#define NQ 2048

typedef unsigned short u16;
typedef __bf16 bf16x8 __attribute__((ext_vector_type(8)));
typedef float f32x4 __attribute__((ext_vector_type(4)));

__device__ __forceinline__ u16 f2bf(float x) {
    unsigned int u = __float_as_uint(x);
    unsigned int r = (u + 0x7fffu + ((u >> 16) & 1u)) >> 16;
    return (u16)r;
}

__device__ __forceinline__ bf16x8 ld_frag(const u16* p) {
    bf16x8 r;
    *reinterpret_cast<uint4*>(&r) = *reinterpret_cast<const uint4*>(p);
    return r;
}

__device__ __forceinline__ void gload_lds16(const u16* g, u16* l) {
    __builtin_amdgcn_global_load_lds((const __attribute__((address_space(1))) void*)g,
                                     (__attribute__((address_space(3))) void*)l, 16, 0, 0);
}

// ---------------- cast x fp32 -> bf16 ----------------
__global__ __launch_bounds__(256) void cast_f32_bf16(const float* __restrict__ in,
                                                     u16* __restrict__ out, int n4) {
    int i = blockIdx.x * 256 + threadIdx.x;
    if (i < n4) {
        float4 v = reinterpret_cast<const float4*>(in)[i];
        ushort4 o;
        o.x = f2bf(v.x); o.y = f2bf(v.y); o.z = f2bf(v.z); o.w = f2bf(v.w);
        reinterpret_cast<ushort4*>(out)[i] = o;
    }
}

// ---------------- transpose-cast W [K][N] fp32 -> [N][K] bf16 ----------------
__global__ __launch_bounds__(256) void transpose_cast(const float* __restrict__ in,
                                                      u16* __restrict__ out, int K, int N) {
    __shared__ u16 t[32][34];
    int k0 = blockIdx.x * 32, n0 = blockIdx.y * 32;
    for (int c = threadIdx.x; c < 1024; c += 256) {
        int k = c >> 5, n = c & 31;
        t[k][n] = f2bf(in[(size_t)(k0 + k) * N + n0 + n]);
    }
    __syncthreads();
    for (int c = threadIdx.x; c < 1024; c += 256) {
        int n = c >> 5, k = c & 31;
        out[(size_t)(n0 + n) * K + k0 + k] = t[k][n];
    }
}

// ---------------- GEMM: C[M,N] fp32 = A[M,K]bf16 @ Bt[N,K]bf16^T ----------------
// m97 structure: global_load_lds width-16 staging, 128x128 tile, BK=32.
// LDS layout swizzled: logical kseg s at row r stored at phys seg s^((r>>1)&3)
// -> fragment ds_read_b128 is 2-way-conflict-free (free per m136).
__global__ __launch_bounds__(256) void gemm_bf16(const u16* __restrict__ A,
                                                 const u16* __restrict__ Bt,
                                                 float* __restrict__ C,
                                                 int M, int N, int K) {
    __shared__ u16 As[128 * 32];
    __shared__ u16 Bs[128 * 32];
    int tid = threadIdx.x;
    int lane = tid & 63, wave = tid >> 6;
    int quad = lane >> 4, l15 = lane & 15;
    int wr = wave >> 1, wc = wave & 1;
    int m0 = blockIdx.y * 128, n0 = blockIdx.x * 128;

    f32x4 zero = {0.f, 0.f, 0.f, 0.f};
    f32x4 acc[4][4];
    for (int i = 0; i < 4; i++)
        for (int j = 0; j < 4; j++) acc[i][j] = zero;

    // staging: chunk ch (16 rows, 1KB) -> lane writes LDS base+16*lane.
    // lane: row = 16*ch + (lane>>2), phys seg = lane&3, fetch logical kseg = phys ^ ((row>>1)&3)
    int r0 = 16 * wave + (lane >> 2);
    int r1 = r0 + 64;
    int ks0 = (lane & 3) ^ ((r0 >> 1) & 3);
    int ks1 = (lane & 3) ^ ((r1 >> 1) & 3);
    const u16* ga0 = A + (size_t)(m0 + r0) * K + ks0 * 8;
    const u16* ga1 = A + (size_t)(m0 + r1) * K + ks1 * 8;
    const u16* gb0 = Bt + (size_t)(n0 + r0) * K + ks0 * 8;
    const u16* gb1 = Bt + (size_t)(n0 + r1) * K + ks1 * 8;
    u16* la0 = &As[wave * 512];
    u16* la1 = &As[(wave + 4) * 512];
    u16* lb0 = &Bs[wave * 512];
    u16* lb1 = &Bs[(wave + 4) * 512];

    int swz = (quad ^ ((l15 >> 1) & 3)) * 8;

    for (int k0 = 0; k0 < K; k0 += 32) {
        __syncthreads();
        gload_lds16(ga0 + k0, la0);
        gload_lds16(ga1 + k0, la1);
        gload_lds16(gb0 + k0, lb0);
        gload_lds16(gb1 + k0, lb1);
        __syncthreads();  // compiler emits vmcnt(0) drain before barrier
        bf16x8 a[4], b[4];
        #pragma unroll
        for (int i = 0; i < 4; i++) a[i] = ld_frag(&As[(64 * wr + 16 * i + l15) * 32 + swz]);
        #pragma unroll
        for (int j = 0; j < 4; j++) b[j] = ld_frag(&Bs[(64 * wc + 16 * j + l15) * 32 + swz]);
        #pragma unroll
        for (int i = 0; i < 4; i++)
            #pragma unroll
            for (int j = 0; j < 4; j++)
                acc[i][j] = __builtin_amdgcn_mfma_f32_16x16x32_bf16(a[i], b[j], acc[i][j], 0, 0, 0);
    }
    for (int i = 0; i < 4; i++) {
        int rowb = m0 + 64 * wr + 16 * i + quad * 4;
        for (int j = 0; j < 4; j++) {
            int col = n0 + 64 * wc + 16 * j + l15;
            for (int r = 0; r < 4; r++)
                C[(size_t)(rowb + r) * N + col] = acc[i][j][r];
        }
    }
}

// ---------------- fused RMSNorm + RoPE, fp32 in -> bf16 head-major out ----------------
__global__ __launch_bounds__(256) void norm_rope(const float* __restrict__ raw,
                                                 const float* __restrict__ cosp,
                                                 const float* __restrict__ sinp,
                                                 const float* __restrict__ w,
                                                 u16* __restrict__ out,
                                                 int T, int nh, float outscale) {
    int wave = threadIdx.x >> 6, lane = threadIdx.x & 63;
    int wid = blockIdx.x * 4 + wave;
    int t = wid / nh, h = wid % nh;
    if (t >= T) return;
    const float* r = raw + (size_t)t * nh * 128 + h * 128;
    float v1 = r[lane], v2 = r[lane + 64];
    float ss = v1 * v1 + v2 * v2;
    for (int off = 1; off < 64; off <<= 1) ss += __shfl_xor(ss, off);
    float inv = rsqrtf(ss * (1.f / 128.f) + 1e-6f);
    float n1 = v1 * inv * w[lane], n2 = v2 * inv * w[lane + 64];
    float c = cosp[(size_t)t * 64 + lane], s = sinp[(size_t)t * 64 + lane];
    float o1 = (n1 * c - n2 * s) * outscale;
    float o2 = (n1 * s + n2 * c) * outscale;
    u16* op = out + ((size_t)h * T + t) * 128;
    op[lane] = f2bf(o1);
    op[lane + 64] = f2bf(o2);
}

// ---------------- V: [T][1024] fp32 -> [h][d][T] bf16 ----------------
__global__ __launch_bounds__(256) void v_transpose(const float* __restrict__ vraw,
                                                   u16* __restrict__ Vbt, int T) {
    __shared__ u16 tt[128][72];
    int h = blockIdx.y, t0 = blockIdx.x * 64;
    for (int c = threadIdx.x; c < 8192; c += 256) {
        int r = c >> 7, d = c & 127;
        tt[d][r] = f2bf(vraw[(size_t)(t0 + r) * HID + h * 128 + d]);
    }
    __syncthreads();
    for (int c = threadIdx.x; c < 8192; c += 256) {
        int d = c >> 6, r = c & 63;
        Vbt[((size_t)h * 128 + d) * T + t0 + r] = tt[d][r];
    }
}

// ---------------- causal MFMA flash attention, Q-tile 128, K-tile 64 ----------------
// 4 waves; wave owns 32 q-rows (2 x 16-row MFMA groups) -> K/V B-frags reused 2x.
// Register prefetch of next K/V tile overlaps global latency with compute.
// Ps round-trip is wave-private (rows 32w..32w+31): lgkmcnt(0) instead of barrier.
__global__ __launch_bounds__(256, 2) void flash_attn(const u16* __restrict__ Qb,
                                                     const u16* __restrict__ Kb,
                                                     const u16* __restrict__ Vbt,
                                                     u16* __restrict__ attn, int T) {
    __shared__ u16 Ks[64][136];
    __shared__ u16 Vt[128][72];
    __shared__ u16 Ps[128][72];
    int tid = threadIdx.x;
    int lane = tid & 63, wave = tid >> 6;
    int quad = lane >> 4, l15 = lane & 15;
    int h = blockIdx.y;
    int qt = (int)gridDim.x - 1 - (int)blockIdx.x;  // heavy blocks first
    int q0 = qt * 128;
    int kvh = h >> 1;

    bf16x8 qf[2][4];
    #pragma unroll
    for (int g = 0; g < 2; g++) {
        const u16* qp = Qb + ((size_t)h * T + q0 + 32 * wave + 16 * g + l15) * 128 + quad * 8;
        #pragma unroll
        for (int kk = 0; kk < 4; kk++) qf[g][kk] = ld_frag(qp + kk * 32);
    }

    f32x4 zero = {0.f, 0.f, 0.f, 0.f};
    float m_i[2][4], l_i[2][4];
    f32x4 o[2][8];
    #pragma unroll
    for (int g = 0; g < 2; g++)
        for (int r = 0; r < 4; r++) { m_i[g][r] = -3.0e38f; l_i[g][r] = 0.f; }
    #pragma unroll
    for (int g = 0; g < 2; g++)
        for (int dt = 0; dt < 8; dt++) o[g][dt] = zero;

    const u16* kbase = Kb + (size_t)kvh * T * 128;
    const u16* vbase = Vbt + (size_t)kvh * 128 * T;
    int ntiles = 2 * qt + 2;
    int myrow0 = q0 + 32 * wave;

    uint4 kpre[4], vpre[4];
    // stage tile 0
    #pragma unroll
    for (int i = 0; i < 4; i++) {
        int c = tid + i * 256;
        kpre[i] = *reinterpret_cast<const uint4*>(kbase + (size_t)(c >> 4) * 128 + (c & 15) * 8);
        vpre[i] = *reinterpret_cast<const uint4*>(vbase + (size_t)(c >> 3) * T + (c & 7) * 8);
    }
    #pragma unroll
    for (int i = 0; i < 4; i++) {
        int c = tid + i * 256;
        *reinterpret_cast<uint4*>(&Ks[c >> 4][(c & 15) * 8]) = kpre[i];
        *reinterpret_cast<uint4*>(&Vt[c >> 3][(c & 7) * 8]) = vpre[i];
    }
    __syncthreads();

    for (int it = 0; it < ntiles; ++it) {
        int s0 = it * 64;
        bool havenext = (it + 1 < ntiles);
        if (havenext) {
            int sn = s0 + 64;
            #pragma unroll
            for (int i = 0; i < 4; i++) {
                int c = tid + i * 256;
                kpre[i] = *reinterpret_cast<const uint4*>(kbase + (size_t)(sn + (c >> 4)) * 128 + (c & 15) * 8);
                vpre[i] = *reinterpret_cast<const uint4*>(vbase + (size_t)(c >> 3) * T + sn + (c & 7) * 8);
            }
        }
        if (s0 <= myrow0 + 31) {  // wave has >=1 unmasked row in this tile
            f32x4 sc[2][4];
            #pragma unroll
            for (int g = 0; g < 2; g++)
                for (int jt = 0; jt < 4; jt++) sc[g][jt] = zero;
            #pragma unroll
            for (int kk = 0; kk < 4; kk++)
                #pragma unroll
                for (int jt = 0; jt < 4; jt++) {
                    bf16x8 b = ld_frag(&Ks[jt * 16 + l15][kk * 32 + quad * 8]);
                    sc[0][jt] = __builtin_amdgcn_mfma_f32_16x16x32_bf16(qf[0][kk], b, sc[0][jt], 0, 0, 0);
                    sc[1][jt] = __builtin_amdgcn_mfma_f32_16x16x32_bf16(qf[1][kk], b, sc[1][jt], 0, 0, 0);
                }

            if (s0 + 63 > myrow0) {  // diagonal region: mask col > row
                #pragma unroll
                for (int g = 0; g < 2; g++)
                    for (int jt = 0; jt < 4; jt++) {
                        int col = s0 + jt * 16 + l15;
                        for (int r = 0; r < 4; r++) {
                            int row = myrow0 + 16 * g + quad * 4 + r;
                            if (col > row) sc[g][jt][r] = -1e30f;
                        }
                    }
            }

            float alpha[2][4];
            #pragma unroll
            for (int g = 0; g < 2; g++)
                for (int r = 0; r < 4; r++) {
                    float mt = fmaxf(fmaxf(sc[g][0][r], sc[g][1][r]), fmaxf(sc[g][2][r], sc[g][3][r]));
                    for (int off = 1; off < 16; off <<= 1) mt = fmaxf(mt, __shfl_xor(mt, off));
                    float mnew = fmaxf(m_i[g][r], mt);
                    alpha[g][r] = __expf(m_i[g][r] - mnew);
                    m_i[g][r] = mnew;
                    float rs = 0.f;
                    for (int jt = 0; jt < 4; jt++) {
                        float p = __expf(sc[g][jt][r] - mnew);
                        sc[g][jt][r] = p;
                        rs += p;
                    }
                    for (int off = 1; off < 16; off <<= 1) rs += __shfl_xor(rs, off);
                    l_i[g][r] = l_i[g][r] * alpha[g][r] + rs;
                }

            #pragma unroll
            for (int g = 0; g < 2; g++)
                for (int jt = 0; jt < 4; jt++)
                    for (int r = 0; r < 4; r++)
                        Ps[32 * wave + 16 * g + quad * 4 + r][jt * 16 + l15] = f2bf(sc[g][jt][r]);
            asm volatile("s_waitcnt lgkmcnt(0)" ::: "memory");  // wave-private Ps ordering

            #pragma unroll
            for (int g = 0; g < 2; g++)
                for (int dt = 0; dt < 8; dt++)
                    for (int r = 0; r < 4; r++) o[g][dt][r] *= alpha[g][r];

            #pragma unroll
            for (int kk2 = 0; kk2 < 2; kk2++) {
                bf16x8 pa0 = ld_frag(&Ps[32 * wave + l15][kk2 * 32 + quad * 8]);
                bf16x8 pa1 = ld_frag(&Ps[32 * wave + 16 + l15][kk2 * 32 + quad * 8]);
                #pragma unroll
                for (int dt = 0; dt < 8; dt++) {
                    bf16x8 vb = ld_frag(&Vt[dt * 16 + l15][kk2 * 32 + quad * 8]);
                    o[0][dt] = __builtin_amdgcn_mfma_f32_16x16x32_bf16(pa0, vb, o[0][dt], 0, 0, 0);
                    o[1][dt] = __builtin_amdgcn_mfma_f32_16x16x32_bf16(pa1, vb, o[1][dt], 0, 0, 0);
                }
            }
        }
        __syncthreads();  // all waves done reading Ks/Vt
        if (havenext) {
            #pragma unroll
            for (int i = 0; i < 4; i++) {
                int c = tid + i * 256;
                *reinterpret_cast<uint4*>(&Ks[c >> 4][(c & 15) * 8]) = kpre[i];
                *reinterpret_cast<uint4*>(&Vt[c >> 3][(c & 7) * 8]) = vpre[i];
            }
            __syncthreads();  // staging visible
        }
    }

    #pragma unroll
    for (int g = 0; g < 2; g++) {
        float inv[4];
        for (int r = 0; r < 4; r++) inv[r] = 1.f / l_i[g][r];
        for (int dt = 0; dt < 8; dt++)
            for (int r = 0; r < 4; r++) {
                int row = q0 + 32 * wave + 16 * g + quad * 4 + r;
                attn[(size_t)row * NQ + h * DHEAD + dt * 16 + l15] = f2bf(o[g][dt][r] * inv[r]);
            }
    }
}

extern "C" void kernel_launch(void* const* d_in, const int* in_sizes, int n_in,
                              void* d_out, int out_size, void* d_ws, size_t ws_size,
                              hipStream_t stream) {
    const float* x    = (const float*)d_in[0];
    const float* cosp = (const float*)d_in[1];
    const float* sinp = (const float*)d_in[2];
    const float* Wq   = (const float*)d_in[3];
    const float* Wk   = (const float*)d_in[4];
    const float* Wv   = (const float*)d_in[5];
    const float* Wo   = (const float*)d_in[6];
    const float* qnw  = (const float*)d_in[7];
    const float* knw  = (const float*)d_in[8];
    float* out = (float*)d_out;
    const int T = in_sizes[1] / 64;  // 4096

    char* ws = (char*)d_ws;
    size_t off = 0;
    auto alloc = [&](size_t bytes) {
        char* p = ws + off;
        off += (bytes + 255) & ~(size_t)255;
        return p;
    };
    u16*   xb   = (u16*)alloc((size_t)T * HID * 2);
    u16*   Wqb  = (u16*)alloc((size_t)NQ * HID * 2);
    u16*   Wkb  = (u16*)alloc((size_t)HID * HID * 2);
    u16*   Wvb  = (u16*)alloc((size_t)HID * HID * 2);
    u16*   Wob  = (u16*)alloc((size_t)HID * NQ * 2);
    float* qraw = (float*)alloc((size_t)T * NQ * 4);
    float* kraw = (float*)alloc((size_t)T * HID * 4);
    float* vraw = (float*)alloc((size_t)T * HID * 4);
    u16*   Qb   = (u16*)alloc((size_t)H2 * T * DHEAD * 2);
    u16*   Kb   = (u16*)alloc((size_t)HKV * T * DHEAD * 2);
    u16*   Vbt  = (u16*)alloc((size_t)HKV * DHEAD * T * 2);
    u16*   attn = (u16*)alloc((size_t)T * NQ * 2);

    cast_f32_bf16<<<(T * HID / 4 + 255) / 256, 256, 0, stream>>>(x, xb, T * HID / 4);
    transpose_cast<<<dim3(HID / 32, NQ / 32), 256, 0, stream>>>(Wq, Wqb, HID, NQ);
    transpose_cast<<<dim3(HID / 32, HID / 32), 256, 0, stream>>>(Wk, Wkb, HID, HID);
    transpose_cast<<<dim3(HID / 32, HID / 32), 256, 0, stream>>>(Wv, Wvb, HID, HID);
    transpose_cast<<<dim3(NQ / 32, HID / 32), 256, 0, stream>>>(Wo, Wob, NQ, HID);

    gemm_bf16<<<dim3(NQ / 128, T / 128), 256, 0, stream>>>(xb, Wqb, qraw, T, NQ, HID);
    gemm_bf16<<<dim3(HID / 128, T / 128), 256, 0, stream>>>(xb, Wkb, kraw, T, HID, HID);
    gemm_bf16<<<dim3(HID / 128, T / 128), 256, 0, stream>>>(xb, Wvb, vraw, T, HID, HID);

    const float scale = 0.08838834764831845f;  // 128^-0.5 folded into Q
    norm_rope<<<T * H2 / 4, 256, 0, stream>>>(qraw, cosp, sinp, qnw, Qb, T, H2, scale);
    norm_rope<<<T * HKV / 4, 256, 0, stream>>>(kraw, cosp, sinp, knw, Kb, T, HKV, 1.0f);
    v_transpose<<<dim3(T / 64, HKV), 256, 0, stream>>>(vraw, Vbt, T);

    flash_attn<<<dim3(T / 128, H2), 256, 0, stream>>>(Qb, Kb, Vbt, attn, T);

    gemm_bf16<<<dim3(HID / 128, T / 128), 256, 0, stream>>>(attn, Wob, out, T, HID, NQ);
}

// Round 4
// 580.491 us; speedup vs baseline: 1.2459x; 1.2459x over previous
//
#include <hip/hip_runtime.h>
#include <hip/hip_bf16.h>

#define H2 16
#define HKV 8
#define DHEAD 128
#define HID 1024
#define NQ 2048

typedef unsigned short u16;
typedef __bf16 bf16x8 __attribute__((ext_vector_type(8)));
typedef float f32x4 __attribute__((ext_vector_type(4)));

__device__ __forceinline__ u16 f2bf(float x) {
    unsigned int u = __float_as_uint(x);
    unsigned int r = (u + 0x7fffu + ((u >> 16) & 1u)) >> 16;
    return (u16)r;
}

__device__ __forceinline__ bf16x8 ld_frag(const u16* p) {
    bf16x8 r;
    *reinterpret_cast<uint4*>(&r) = *reinterpret_cast<const uint4*>(p);
    return r;
}

__device__ __forceinline__ void gload_lds16(const u16* g, u16* l) {
    __builtin_amdgcn_global_load_lds((const __attribute__((address_space(1))) void*)g,
                                     (__attribute__((address_space(3))) void*)l, 16, 0, 0);
}

// ---------------- cast x fp32 -> bf16 ----------------
__global__ __launch_bounds__(256) void cast_f32_bf16(const float* __restrict__ in,
                                                     u16* __restrict__ out, int n4) {
    int i = blockIdx.x * 256 + threadIdx.x;
    if (i < n4) {
        float4 v = reinterpret_cast<const float4*>(in)[i];
        ushort4 o;
        o.x = f2bf(v.x); o.y = f2bf(v.y); o.z = f2bf(v.z); o.w = f2bf(v.w);
        reinterpret_cast<ushort4*>(out)[i] = o;
    }
}

// ---------------- transpose-cast W [K][N] fp32 -> [N][K] bf16 ----------------
__global__ __launch_bounds__(256) void transpose_cast(const float* __restrict__ in,
                                                      u16* __restrict__ out, int K, int N) {
    __shared__ u16 t[32][34];
    int k0 = blockIdx.x * 32, n0 = blockIdx.y * 32;
    for (int c = threadIdx.x; c < 1024; c += 256) {
        int k = c >> 5, n = c & 31;
        t[k][n] = f2bf(in[(size_t)(k0 + k) * N + n0 + n]);
    }
    __syncthreads();
    for (int c = threadIdx.x; c < 1024; c += 256) {
        int n = c >> 5, k = c & 31;
        out[(size_t)(n0 + n) * K + k0 + k] = t[k][n];
    }
}

// ---------------- GEMM: C[M,N] fp32 = A[M,K]bf16 @ Bt[N,K]bf16^T ----------------
__global__ __launch_bounds__(256) void gemm_bf16(const u16* __restrict__ A,
                                                 const u16* __restrict__ Bt,
                                                 float* __restrict__ C,
                                                 int M, int N, int K) {
    __shared__ u16 As[128 * 32];
    __shared__ u16 Bs[128 * 32];
    int tid = threadIdx.x;
    int lane = tid & 63, wave = tid >> 6;
    int quad = lane >> 4, l15 = lane & 15;
    int wr = wave >> 1, wc = wave & 1;
    int m0 = blockIdx.y * 128, n0 = blockIdx.x * 128;

    f32x4 zero = {0.f, 0.f, 0.f, 0.f};
    f32x4 acc[4][4];
    for (int i = 0; i < 4; i++)
        for (int j = 0; j < 4; j++) acc[i][j] = zero;

    int r0 = 16 * wave + (lane >> 2);
    int r1 = r0 + 64;
    int ks0 = (lane & 3) ^ ((r0 >> 1) & 3);
    int ks1 = (lane & 3) ^ ((r1 >> 1) & 3);
    const u16* ga0 = A + (size_t)(m0 + r0) * K + ks0 * 8;
    const u16* ga1 = A + (size_t)(m0 + r1) * K + ks1 * 8;
    const u16* gb0 = Bt + (size_t)(n0 + r0) * K + ks0 * 8;
    const u16* gb1 = Bt + (size_t)(n0 + r1) * K + ks1 * 8;
    u16* la0 = &As[wave * 512];
    u16* la1 = &As[(wave + 4) * 512];
    u16* lb0 = &Bs[wave * 512];
    u16* lb1 = &Bs[(wave + 4) * 512];

    int swz = (quad ^ ((l15 >> 1) & 3)) * 8;

    for (int k0 = 0; k0 < K; k0 += 32) {
        __syncthreads();
        gload_lds16(ga0 + k0, la0);
        gload_lds16(ga1 + k0, la1);
        gload_lds16(gb0 + k0, lb0);
        gload_lds16(gb1 + k0, lb1);
        __syncthreads();
        bf16x8 a[4], b[4];
        #pragma unroll
        for (int i = 0; i < 4; i++) a[i] = ld_frag(&As[(64 * wr + 16 * i + l15) * 32 + swz]);
        #pragma unroll
        for (int j = 0; j < 4; j++) b[j] = ld_frag(&Bs[(64 * wc + 16 * j + l15) * 32 + swz]);
        #pragma unroll
        for (int i = 0; i < 4; i++)
            #pragma unroll
            for (int j = 0; j < 4; j++)
                acc[i][j] = __builtin_amdgcn_mfma_f32_16x16x32_bf16(a[i], b[j], acc[i][j], 0, 0, 0);
    }
    for (int i = 0; i < 4; i++) {
        int rowb = m0 + 64 * wr + 16 * i + quad * 4;
        for (int j = 0; j < 4; j++) {
            int col = n0 + 64 * wc + 16 * j + l15;
            for (int r = 0; r < 4; r++)
                C[(size_t)(rowb + r) * N + col] = acc[i][j][r];
        }
    }
}

// ---------------- fused RMSNorm + RoPE, fp32 in -> bf16 head-major out ----------------
__global__ __launch_bounds__(256) void norm_rope(const float* __restrict__ raw,
                                                 const float* __restrict__ cosp,
                                                 const float* __restrict__ sinp,
                                                 const float* __restrict__ w,
                                                 u16* __restrict__ out,
                                                 int T, int nh, float outscale) {
    int wave = threadIdx.x >> 6, lane = threadIdx.x & 63;
    int wid = blockIdx.x * 4 + wave;
    int t = wid / nh, h = wid % nh;
    if (t >= T) return;
    const float* r = raw + (size_t)t * nh * 128 + h * 128;
    float v1 = r[lane], v2 = r[lane + 64];
    float ss = v1 * v1 + v2 * v2;
    for (int off = 1; off < 64; off <<= 1) ss += __shfl_xor(ss, off);
    float inv = rsqrtf(ss * (1.f / 128.f) + 1e-6f);
    float n1 = v1 * inv * w[lane], n2 = v2 * inv * w[lane + 64];
    float c = cosp[(size_t)t * 64 + lane], s = sinp[(size_t)t * 64 + lane];
    float o1 = (n1 * c - n2 * s) * outscale;
    float o2 = (n1 * s + n2 * c) * outscale;
    u16* op = out + ((size_t)h * T + t) * 128;
    op[lane] = f2bf(o1);
    op[lane + 64] = f2bf(o2);
}

// ---------------- V: [T][1024] fp32 -> [h][d][T] bf16 ----------------
__global__ __launch_bounds__(256) void v_transpose(const float* __restrict__ vraw,
                                                   u16* __restrict__ Vbt, int T) {
    __shared__ u16 tt[128][72];
    int h = blockIdx.y, t0 = blockIdx.x * 64;
    for (int c = threadIdx.x; c < 8192; c += 256) {
        int r = c >> 7, d = c & 127;
        tt[d][r] = f2bf(vraw[(size_t)(t0 + r) * HID + h * 128 + d]);
    }
    __syncthreads();
    for (int c = threadIdx.x; c < 8192; c += 256) {
        int d = c >> 6, r = c & 63;
        Vbt[((size_t)h * 128 + d) * T + t0 + r] = tt[d][r];
    }
}

// ---------------- causal MFMA flash attention, Q-tile 64, swizzled 40KB LDS ----------------
// LDS = Ks 16K + Vt 16K + Ps 8K = 40960 B -> 4 blocks/CU (exactly 160 KiB).
// Phys 16B-seg = logical-seg ^ (row&7): frag ds_read_b128 lands 2-way (free, m136)
// and the unpadded layout satisfies global_load_lds's uniform-base+lane*16 rule.
// 2 barriers/iter; Ps round-trip is wave-private -> lgkmcnt(0) only.
__global__ __launch_bounds__(256) void flash_attn(const u16* __restrict__ Qb,
                                                  const u16* __restrict__ Kb,
                                                  const u16* __restrict__ Vbt,
                                                  u16* __restrict__ attn, int T) {
    __shared__ u16 Ks[64 * 128];
    __shared__ u16 Vt[128 * 64];
    __shared__ u16 Ps[64 * 64];
    int tid = threadIdx.x;
    int lane = tid & 63, wave = tid >> 6;
    int quad = lane >> 4, l15 = lane & 15;
    int swb8 = (l15 & 7) * 8;  // row-XOR term, since (s^x)*8 == s*8 ^ x*8
    int h = blockIdx.y;
    int qt = (int)gridDim.x - 1 - (int)blockIdx.x;  // heavy blocks first
    int q0 = qt * 64;
    int kvh = h >> 1;

    bf16x8 qf[4];
    {
        const u16* qp = Qb + ((size_t)h * T + q0 + 16 * wave + l15) * 128 + quad * 8;
        #pragma unroll
        for (int kk = 0; kk < 4; kk++) qf[kk] = ld_frag(qp + kk * 32);
    }

    f32x4 zero = {0.f, 0.f, 0.f, 0.f};
    float m_i[4], l_i[4];
    f32x4 o[8];
    for (int r = 0; r < 4; r++) { m_i[r] = -3.0e38f; l_i[r] = 0.f; }
    for (int dt = 0; dt < 8; dt++) o[dt] = zero;

    const u16* kbase = Kb + (size_t)kvh * T * 128;
    const u16* vbase = Vbt + (size_t)kvh * 128 * T;

    // staging addresses (chunk = wave*4+i, 1KB each; swizzled logical seg)
    int krow_ = (lane >> 4);           // + ch*4
    int kseg_ = (lane & 15);
    int vrow_ = (lane >> 3);           // + ch*8
    int vseg_ = (lane & 7);

    for (int s0 = 0; s0 <= q0; s0 += 64) {
        __syncthreads();  // prev-iter readers done
        #pragma unroll
        for (int i = 0; i < 4; i++) {
            int ch = wave * 4 + i;
            int r = ch * 4 + krow_;
            int s = kseg_ ^ (r & 7);
            gload_lds16(kbase + (size_t)(s0 + r) * 128 + s * 8, &Ks[ch * 512]);
        }
        #pragma unroll
        for (int i = 0; i < 4; i++) {
            int ch = wave * 4 + i;
            int d = ch * 8 + vrow_;
            int s = vseg_ ^ (d & 7);
            gload_lds16(vbase + (size_t)d * T + s0 + s * 8, &Vt[ch * 512]);
        }
        __syncthreads();  // vmcnt drain + visibility

        f32x4 sc[4];
        for (int jt = 0; jt < 4; jt++) sc[jt] = zero;
        #pragma unroll
        for (int kk = 0; kk < 4; kk++)
            #pragma unroll
            for (int jt = 0; jt < 4; jt++) {
                bf16x8 b = ld_frag(&Ks[(jt * 16 + l15) * 128 + ((kk * 32 + quad * 8) ^ swb8)]);
                sc[jt] = __builtin_amdgcn_mfma_f32_16x16x32_bf16(qf[kk], b, sc[jt], 0, 0, 0);
            }

        if (s0 == q0) {  // diagonal tile: mask col > row
            #pragma unroll
            for (int jt = 0; jt < 4; jt++) {
                int col = jt * 16 + l15;
                for (int r = 0; r < 4; r++) {
                    int row = 16 * wave + quad * 4 + r;
                    if (col > row) sc[jt][r] = -1e30f;
                }
            }
        }

        float alpha[4];
        #pragma unroll
        for (int r = 0; r < 4; r++) {
            float mt = fmaxf(fmaxf(sc[0][r], sc[1][r]), fmaxf(sc[2][r], sc[3][r]));
            for (int off = 1; off < 16; off <<= 1) mt = fmaxf(mt, __shfl_xor(mt, off));
            float mnew = fmaxf(m_i[r], mt);
            alpha[r] = __expf(m_i[r] - mnew);
            m_i[r] = mnew;
            float rs = 0.f;
            for (int jt = 0; jt < 4; jt++) {
                float p = __expf(sc[jt][r] - mnew);
                sc[jt][r] = p;
                rs += p;
            }
            for (int off = 1; off < 16; off <<= 1) rs += __shfl_xor(rs, off);
            l_i[r] = l_i[r] * alpha[r] + rs;
        }

        #pragma unroll
        for (int jt = 0; jt < 4; jt++)
            for (int r = 0; r < 4; r++) {
                int pr = 16 * wave + quad * 4 + r;
                int cb = jt * 16 + l15;
                Ps[pr * 64 + ((((cb >> 3) ^ (pr & 7)) << 3) | (cb & 7))] = f2bf(sc[jt][r]);
            }
        asm volatile("s_waitcnt lgkmcnt(0)" ::: "memory");  // wave-private Ps ordering

        #pragma unroll
        for (int dt = 0; dt < 8; dt++)
            for (int r = 0; r < 4; r++) o[dt][r] *= alpha[r];

        #pragma unroll
        for (int kk2 = 0; kk2 < 2; kk2++) {
            bf16x8 pa = ld_frag(&Ps[(16 * wave + l15) * 64 + ((kk2 * 32 + quad * 8) ^ swb8)]);
            #pragma unroll
            for (int dt = 0; dt < 8; dt++) {
                bf16x8 vb = ld_frag(&Vt[(dt * 16 + l15) * 64 + ((kk2 * 32 + quad * 8) ^ swb8)]);
                o[dt] = __builtin_amdgcn_mfma_f32_16x16x32_bf16(pa, vb, o[dt], 0, 0, 0);
            }
        }
    }

    float inv[4];
    for (int r = 0; r < 4; r++) inv[r] = 1.f / l_i[r];
    for (int dt = 0; dt < 8; dt++)
        for (int r = 0; r < 4; r++) {
            int row = q0 + 16 * wave + quad * 4 + r;
            attn[(size_t)row * NQ + h * DHEAD + dt * 16 + l15] = f2bf(o[dt][r] * inv[r]);
        }
}

extern "C" void kernel_launch(void* const* d_in, const int* in_sizes, int n_in,
                              void* d_out, int out_size, void* d_ws, size_t ws_size,
                              hipStream_t stream) {
    const float* x    = (const float*)d_in[0];
    const float* cosp = (const float*)d_in[1];
    const float* sinp = (const float*)d_in[2];
    const float* Wq   = (const float*)d_in[3];
    const float* Wk   = (const float*)d_in[4];
    const float* Wv   = (const float*)d_in[5];
    const float* Wo   = (const float*)d_in[6];
    const float* qnw  = (const float*)d_in[7];
    const float* knw  = (const float*)d_in[8];
    float* out = (float*)d_out;
    const int T = in_sizes[1] / 64;  // 4096

    char* ws = (char*)d_ws;
    size_t off = 0;
    auto alloc = [&](size_t bytes) {
        char* p = ws + off;
        off += (bytes + 255) & ~(size_t)255;
        return p;
    };
    u16*   xb   = (u16*)alloc((size_t)T * HID * 2);
    u16*   Wqb  = (u16*)alloc((size_t)NQ * HID * 2);
    u16*   Wkb  = (u16*)alloc((size_t)HID * HID * 2);
    u16*   Wvb  = (u16*)alloc((size_t)HID * HID * 2);
    u16*   Wob  = (u16*)alloc((size_t)HID * NQ * 2);
    float* qraw = (float*)alloc((size_t)T * NQ * 4);
    float* kraw = (float*)alloc((size_t)T * HID * 4);
    float* vraw = (float*)alloc((size_t)T * HID * 4);
    u16*   Qb   = (u16*)alloc((size_t)H2 * T * DHEAD * 2);
    u16*   Kb   = (u16*)alloc((size_t)HKV * T * DHEAD * 2);
    u16*   Vbt  = (u16*)alloc((size_t)HKV * DHEAD * T * 2);
    u16*   attn = (u16*)alloc((size_t)T * NQ * 2);

    cast_f32_bf16<<<(T * HID / 4 + 255) / 256, 256, 0, stream>>>(x, xb, T * HID / 4);
    transpose_cast<<<dim3(HID / 32, NQ / 32), 256, 0, stream>>>(Wq, Wqb, HID, NQ);
    transpose_cast<<<dim3(HID / 32, HID / 32), 256, 0, stream>>>(Wk, Wkb, HID, HID);
    transpose_cast<<<dim3(HID / 32, HID / 32), 256, 0, stream>>>(Wv, Wvb, HID, HID);
    transpose_cast<<<dim3(NQ / 32, HID / 32), 256, 0, stream>>>(Wo, Wob, NQ, HID);

    gemm_bf16<<<dim3(NQ / 128, T / 128), 256, 0, stream>>>(xb, Wqb, qraw, T, NQ, HID);
    gemm_bf16<<<dim3(HID / 128, T / 128), 256, 0, stream>>>(xb, Wkb, kraw, T, HID, HID);
    gemm_bf16<<<dim3(HID / 128, T / 128), 256, 0, stream>>>(xb, Wvb, vraw, T, HID, HID);

    const float scale = 0.08838834764831845f;  // 128^-0.5 folded into Q
    norm_rope<<<T * H2 / 4, 256, 0, stream>>>(qraw, cosp, sinp, qnw, Qb, T, H2, scale);
    norm_rope<<<T * HKV / 4, 256, 0, stream>>>(kraw, cosp, sinp, knw, Kb, T, HKV, 1.0f);
    v_transpose<<<dim3(T / 64, HKV), 256, 0, stream>>>(vraw, Vbt, T);

    flash_attn<<<dim3(T / 64, H2), 256, 0, stream>>>(Qb, Kb, Vbt, attn, T);

    gemm_bf16<<<dim3(HID / 128, T / 128), 256, 0, stream>>>(attn, Wob, out, T, HID, NQ);
}

// Round 5
// 547.503 us; speedup vs baseline: 1.3210x; 1.0603x over previous
//
#include <hip/hip_runtime.h>
#include <hip/hip_bf16.h>

#define H2 16
#define HKV 8
#define DHEAD 128
#define HID 1024
#define NQ 2048

typedef unsigned short u16;
typedef __bf16 bf16x8 __attribute__((ext_vector_type(8)));
typedef float f32x4 __attribute__((ext_vector_type(4)));

__device__ __forceinline__ u16 f2bf(float x) {
    unsigned int u = __float_as_uint(x);
    unsigned int r = (u + 0x7fffu + ((u >> 16) & 1u)) >> 16;
    return (u16)r;
}

__device__ __forceinline__ bf16x8 ld_frag(const u16* p) {
    bf16x8 r;
    *reinterpret_cast<uint4*>(&r) = *reinterpret_cast<const uint4*>(p);
    return r;
}

__device__ __forceinline__ void gload_lds16(const u16* g, u16* l) {
    __builtin_amdgcn_global_load_lds((const __attribute__((address_space(1))) void*)g,
                                     (__attribute__((address_space(3))) void*)l, 16, 0, 0);
}

// ---------------- cast x fp32 -> bf16 ----------------
__global__ __launch_bounds__(256) void cast_f32_bf16(const float* __restrict__ in,
                                                     u16* __restrict__ out, int n4) {
    int i = blockIdx.x * 256 + threadIdx.x;
    if (i < n4) {
        float4 v = reinterpret_cast<const float4*>(in)[i];
        ushort4 o;
        o.x = f2bf(v.x); o.y = f2bf(v.y); o.z = f2bf(v.z); o.w = f2bf(v.w);
        reinterpret_cast<ushort4*>(out)[i] = o;
    }
}

// ---------------- transpose-cast W [K][N] fp32 -> [N][K] bf16 ----------------
__global__ __launch_bounds__(256) void transpose_cast(const float* __restrict__ in,
                                                      u16* __restrict__ out, int K, int N) {
    __shared__ u16 t[32][34];
    int k0 = blockIdx.x * 32, n0 = blockIdx.y * 32;
    for (int c = threadIdx.x; c < 1024; c += 256) {
        int k = c >> 5, n = c & 31;
        t[k][n] = f2bf(in[(size_t)(k0 + k) * N + n0 + n]);
    }
    __syncthreads();
    for (int c = threadIdx.x; c < 1024; c += 256) {
        int n = c >> 5, k = c & 31;
        out[(size_t)(n0 + n) * K + k0 + k] = t[k][n];
    }
}

// ---------------- GEMM: C[M,N] fp32 = A[M,K]bf16 @ Bt[N,K]bf16^T ----------------
__global__ __launch_bounds__(256) void gemm_bf16(const u16* __restrict__ A,
                                                 const u16* __restrict__ Bt,
                                                 float* __restrict__ C,
                                                 int M, int N, int K) {
    __shared__ u16 As[128 * 32];
    __shared__ u16 Bs[128 * 32];
    int tid = threadIdx.x;
    int lane = tid & 63, wave = tid >> 6;
    int quad = lane >> 4, l15 = lane & 15;
    int wr = wave >> 1, wc = wave & 1;
    int m0 = blockIdx.y * 128, n0 = blockIdx.x * 128;

    f32x4 zero = {0.f, 0.f, 0.f, 0.f};
    f32x4 acc[4][4];
    for (int i = 0; i < 4; i++)
        for (int j = 0; j < 4; j++) acc[i][j] = zero;

    int r0 = 16 * wave + (lane >> 2);
    int r1 = r0 + 64;
    int ks0 = (lane & 3) ^ ((r0 >> 1) & 3);
    int ks1 = (lane & 3) ^ ((r1 >> 1) & 3);
    const u16* ga0 = A + (size_t)(m0 + r0) * K + ks0 * 8;
    const u16* ga1 = A + (size_t)(m0 + r1) * K + ks1 * 8;
    const u16* gb0 = Bt + (size_t)(n0 + r0) * K + ks0 * 8;
    const u16* gb1 = Bt + (size_t)(n0 + r1) * K + ks1 * 8;
    u16* la0 = &As[wave * 512];
    u16* la1 = &As[(wave + 4) * 512];
    u16* lb0 = &Bs[wave * 512];
    u16* lb1 = &Bs[(wave + 4) * 512];

    int swz = (quad ^ ((l15 >> 1) & 3)) * 8;

    for (int k0 = 0; k0 < K; k0 += 32) {
        __syncthreads();
        gload_lds16(ga0 + k0, la0);
        gload_lds16(ga1 + k0, la1);
        gload_lds16(gb0 + k0, lb0);
        gload_lds16(gb1 + k0, lb1);
        __syncthreads();
        bf16x8 a[4], b[4];
        #pragma unroll
        for (int i = 0; i < 4; i++) a[i] = ld_frag(&As[(64 * wr + 16 * i + l15) * 32 + swz]);
        #pragma unroll
        for (int j = 0; j < 4; j++) b[j] = ld_frag(&Bs[(64 * wc + 16 * j + l15) * 32 + swz]);
        #pragma unroll
        for (int i = 0; i < 4; i++)
            #pragma unroll
            for (int j = 0; j < 4; j++)
                acc[i][j] = __builtin_amdgcn_mfma_f32_16x16x32_bf16(a[i], b[j], acc[i][j], 0, 0, 0);
    }
    for (int i = 0; i < 4; i++) {
        int rowb = m0 + 64 * wr + 16 * i + quad * 4;
        for (int j = 0; j < 4; j++) {
            int col = n0 + 64 * wc + 16 * j + l15;
            for (int r = 0; r < 4; r++)
                C[(size_t)(rowb + r) * N + col] = acc[i][j][r];
        }
    }
}

// ---------------- fused RMSNorm + RoPE, fp32 in -> bf16 head-major out ----------------
__global__ __launch_bounds__(256) void norm_rope(const float* __restrict__ raw,
                                                 const float* __restrict__ cosp,
                                                 const float* __restrict__ sinp,
                                                 const float* __restrict__ w,
                                                 u16* __restrict__ out,
                                                 int T, int nh, float outscale) {
    int wave = threadIdx.x >> 6, lane = threadIdx.x & 63;
    int wid = blockIdx.x * 4 + wave;
    int t = wid / nh, h = wid % nh;
    if (t >= T) return;
    const float* r = raw + (size_t)t * nh * 128 + h * 128;
    float v1 = r[lane], v2 = r[lane + 64];
    float ss = v1 * v1 + v2 * v2;
    for (int off = 1; off < 64; off <<= 1) ss += __shfl_xor(ss, off);
    float inv = rsqrtf(ss * (1.f / 128.f) + 1e-6f);
    float n1 = v1 * inv * w[lane], n2 = v2 * inv * w[lane + 64];
    float c = cosp[(size_t)t * 64 + lane], s = sinp[(size_t)t * 64 + lane];
    float o1 = (n1 * c - n2 * s) * outscale;
    float o2 = (n1 * s + n2 * c) * outscale;
    u16* op = out + ((size_t)h * T + t) * 128;
    op[lane] = f2bf(o1);
    op[lane + 64] = f2bf(o2);
}

// ---------------- V: [T][1024] fp32 -> [h][d][T] bf16 ----------------
__global__ __launch_bounds__(256) void v_transpose(const float* __restrict__ vraw,
                                                   u16* __restrict__ Vbt, int T) {
    __shared__ u16 tt[128][72];
    int h = blockIdx.y, t0 = blockIdx.x * 64;
    for (int c = threadIdx.x; c < 8192; c += 256) {
        int r = c >> 7, d = c & 127;
        tt[d][r] = f2bf(vraw[(size_t)(t0 + r) * HID + h * 128 + d]);
    }
    __syncthreads();
    for (int c = threadIdx.x; c < 8192; c += 256) {
        int d = c >> 6, r = c & 63;
        Vbt[((size_t)h * 128 + d) * T + t0 + r] = tt[d][r];
    }
}

// ---------------- causal MFMA flash attention, async-pipelined ----------------
// Double-buffered Ks/Vt (72 KB LDS): issue global_load_lds for tile i+1, compute
// tile i, then ONE __syncthreads — its vmcnt(0) drain lands after compute, so
// staging latency overlaps QK+softmax+PV. Row-sum of P folded into the MFMA
// pipe via an all-ones B fragment (lsum), deleting the sum shuffle-reduce.
__global__ __launch_bounds__(256) void flash_attn(const u16* __restrict__ Qb,
                                                  const u16* __restrict__ Kb,
                                                  const u16* __restrict__ Vbt,
                                                  u16* __restrict__ attn, int T) {
    __shared__ u16 Ks[2][64 * 128];
    __shared__ u16 Vt[2][128 * 64];
    __shared__ u16 Ps[64 * 64];
    int tid = threadIdx.x;
    int lane = tid & 63, wave = tid >> 6;
    int quad = lane >> 4, l15 = lane & 15;
    int swb8 = (l15 & 7) * 8;  // row-XOR term: (s^x)*8 == s*8 ^ x*8
    int h = blockIdx.y;
    int qt = (int)gridDim.x - 1 - (int)blockIdx.x;  // heavy blocks first
    int q0 = qt * 64;
    int kvh = h >> 1;

    bf16x8 qf[4];
    {
        const u16* qp = Qb + ((size_t)h * T + q0 + 16 * wave + l15) * 128 + quad * 8;
        #pragma unroll
        for (int kk = 0; kk < 4; kk++) qf[kk] = ld_frag(qp + kk * 32);
    }
    bf16x8 onesf;
    #pragma unroll
    for (int i = 0; i < 8; i++) onesf[i] = (__bf16)1.0f;

    f32x4 zero = {0.f, 0.f, 0.f, 0.f};
    float m_i[4];
    f32x4 lsum = zero;
    f32x4 o[8];
    for (int r = 0; r < 4; r++) m_i[r] = -3.0e38f;
    for (int dt = 0; dt < 8; dt++) o[dt] = zero;

    const u16* kbase = Kb + (size_t)kvh * T * 128;
    const u16* vbase = Vbt + (size_t)kvh * 128 * T;

    int krow_ = (lane >> 4);
    int kseg_ = (lane & 15);
    int vrow_ = (lane >> 3);
    int vseg_ = (lane & 7);

    auto stage = [&](int s0, int b) {
        #pragma unroll
        for (int i = 0; i < 4; i++) {
            int ch = wave * 4 + i;
            int r = ch * 4 + krow_;
            int s = kseg_ ^ (r & 7);
            gload_lds16(kbase + (size_t)(s0 + r) * 128 + s * 8, &Ks[b][ch * 512]);
        }
        #pragma unroll
        for (int i = 0; i < 4; i++) {
            int ch = wave * 4 + i;
            int d = ch * 8 + vrow_;
            int s = vseg_ ^ (d & 7);
            gload_lds16(vbase + (size_t)d * T + s0 + s * 8, &Vt[b][ch * 512]);
        }
    };

    int ntiles = qt + 1;
    stage(0, 0);
    __syncthreads();  // vmcnt(0): tile 0 resident

    for (int it = 0; it < ntiles; ++it) {
        int b = it & 1;
        if (it + 1 < ntiles) stage((it + 1) * 64, 1 - b);  // async into other buffer
        int s0 = it * 64;

        f32x4 sc[4];
        for (int jt = 0; jt < 4; jt++) sc[jt] = zero;
        #pragma unroll
        for (int kk = 0; kk < 4; kk++)
            #pragma unroll
            for (int jt = 0; jt < 4; jt++) {
                bf16x8 bfrag = ld_frag(&Ks[b][(jt * 16 + l15) * 128 + ((kk * 32 + quad * 8) ^ swb8)]);
                sc[jt] = __builtin_amdgcn_mfma_f32_16x16x32_bf16(qf[kk], bfrag, sc[jt], 0, 0, 0);
            }

        if (s0 == q0) {  // diagonal tile: mask col > row
            #pragma unroll
            for (int jt = 0; jt < 4; jt++) {
                int col = jt * 16 + l15;
                for (int r = 0; r < 4; r++) {
                    int row = 16 * wave + quad * 4 + r;
                    if (col > row) sc[jt][r] = -1e30f;
                }
            }
        }

        float alpha[4];
        #pragma unroll
        for (int r = 0; r < 4; r++) {
            float mt = fmaxf(fmaxf(sc[0][r], sc[1][r]), fmaxf(sc[2][r], sc[3][r]));
            for (int off = 1; off < 16; off <<= 1) mt = fmaxf(mt, __shfl_xor(mt, off));
            float mnew = fmaxf(m_i[r], mt);
            alpha[r] = __expf(m_i[r] - mnew);
            m_i[r] = mnew;
            for (int jt = 0; jt < 4; jt++)
                sc[jt][r] = __expf(sc[jt][r] - mnew);
        }

        #pragma unroll
        for (int jt = 0; jt < 4; jt++)
            for (int r = 0; r < 4; r++) {
                int pr = 16 * wave + quad * 4 + r;
                int cb = jt * 16 + l15;
                Ps[pr * 64 + ((((cb >> 3) ^ (pr & 7)) << 3) | (cb & 7))] = f2bf(sc[jt][r]);
            }
        asm volatile("s_waitcnt lgkmcnt(0)" ::: "memory");  // wave-private Ps ordering

        #pragma unroll
        for (int r = 0; r < 4; r++) lsum[r] *= alpha[r];
        #pragma unroll
        for (int dt = 0; dt < 8; dt++)
            for (int r = 0; r < 4; r++) o[dt][r] *= alpha[r];

        #pragma unroll
        for (int kk2 = 0; kk2 < 2; kk2++) {
            bf16x8 pa = ld_frag(&Ps[(16 * wave + l15) * 64 + ((kk2 * 32 + quad * 8) ^ swb8)]);
            lsum = __builtin_amdgcn_mfma_f32_16x16x32_bf16(pa, onesf, lsum, 0, 0, 0);
            #pragma unroll
            for (int dt = 0; dt < 8; dt++) {
                bf16x8 vb = ld_frag(&Vt[b][(dt * 16 + l15) * 64 + ((kk2 * 32 + quad * 8) ^ swb8)]);
                o[dt] = __builtin_amdgcn_mfma_f32_16x16x32_bf16(pa, vb, o[dt], 0, 0, 0);
            }
        }
        __syncthreads();  // drains next-tile loads (post-compute) + buffer handoff
    }

    float inv[4];
    for (int r = 0; r < 4; r++) inv[r] = 1.f / lsum[r];
    for (int dt = 0; dt < 8; dt++)
        for (int r = 0; r < 4; r++) {
            int row = q0 + 16 * wave + quad * 4 + r;
            attn[(size_t)row * NQ + h * DHEAD + dt * 16 + l15] = f2bf(o[dt][r] * inv[r]);
        }
}

extern "C" void kernel_launch(void* const* d_in, const int* in_sizes, int n_in,
                              void* d_out, int out_size, void* d_ws, size_t ws_size,
                              hipStream_t stream) {
    const float* x    = (const float*)d_in[0];
    const float* cosp = (const float*)d_in[1];
    const float* sinp = (const float*)d_in[2];
    const float* Wq   = (const float*)d_in[3];
    const float* Wk   = (const float*)d_in[4];
    const float* Wv   = (const float*)d_in[5];
    const float* Wo   = (const float*)d_in[6];
    const float* qnw  = (const float*)d_in[7];
    const float* knw  = (const float*)d_in[8];
    float* out = (float*)d_out;
    const int T = in_sizes[1] / 64;  // 4096

    char* ws = (char*)d_ws;
    size_t off = 0;
    auto alloc = [&](size_t bytes) {
        char* p = ws + off;
        off += (bytes + 255) & ~(size_t)255;
        return p;
    };
    u16*   xb   = (u16*)alloc((size_t)T * HID * 2);
    u16*   Wqb  = (u16*)alloc((size_t)NQ * HID * 2);
    u16*   Wkb  = (u16*)alloc((size_t)HID * HID * 2);
    u16*   Wvb  = (u16*)alloc((size_t)HID * HID * 2);
    u16*   Wob  = (u16*)alloc((size_t)HID * NQ * 2);
    float* qraw = (float*)alloc((size_t)T * NQ * 4);
    float* kraw = (float*)alloc((size_t)T * HID * 4);
    float* vraw = (float*)alloc((size_t)T * HID * 4);
    u16*   Qb   = (u16*)alloc((size_t)H2 * T * DHEAD * 2);
    u16*   Kb   = (u16*)alloc((size_t)HKV * T * DHEAD * 2);
    u16*   Vbt  = (u16*)alloc((size_t)HKV * DHEAD * T * 2);
    u16*   attn = (u16*)alloc((size_t)T * NQ * 2);

    cast_f32_bf16<<<(T * HID / 4 + 255) / 256, 256, 0, stream>>>(x, xb, T * HID / 4);
    transpose_cast<<<dim3(HID / 32, NQ / 32), 256, 0, stream>>>(Wq, Wqb, HID, NQ);
    transpose_cast<<<dim3(HID / 32, HID / 32), 256, 0, stream>>>(Wk, Wkb, HID, HID);
    transpose_cast<<<dim3(HID / 32, HID / 32), 256, 0, stream>>>(Wv, Wvb, HID, HID);
    transpose_cast<<<dim3(NQ / 32, HID / 32), 256, 0, stream>>>(Wo, Wob, NQ, HID);

    gemm_bf16<<<dim3(NQ / 128, T / 128), 256, 0, stream>>>(xb, Wqb, qraw, T, NQ, HID);
    gemm_bf16<<<dim3(HID / 128, T / 128), 256, 0, stream>>>(xb, Wkb, kraw, T, HID, HID);
    gemm_bf16<<<dim3(HID / 128, T / 128), 256, 0, stream>>>(xb, Wvb, vraw, T, HID, HID);

    const float scale = 0.08838834764831845f;  // 128^-0.5 folded into Q
    norm_rope<<<T * H2 / 4, 256, 0, stream>>>(qraw, cosp, sinp, qnw, Qb, T, H2, scale);
    norm_rope<<<T * HKV / 4, 256, 0, stream>>>(kraw, cosp, sinp, knw, Kb, T, HKV, 1.0f);
    v_transpose<<<dim3(T / 64, HKV), 256, 0, stream>>>(vraw, Vbt, T);

    flash_attn<<<dim3(T / 64, H2), 256, 0, stream>>>(Qb, Kb, Vbt, attn, T);

    gemm_bf16<<<dim3(HID / 128, T / 128), 256, 0, stream>>>(attn, Wob, out, T, HID, NQ);
}

// Round 6
// 427.941 us; speedup vs baseline: 1.6900x; 1.2794x over previous
//
#include <hip/hip_runtime.h>
#include <hip/hip_bf16.h>

#define H2 16
#define HKV 8
#define DHEAD 128
#define HID 1024
#define NQ 2048

typedef unsigned short u16;
typedef __bf16 bf16x8 __attribute__((ext_vector_type(8)));
typedef float f32x4 __attribute__((ext_vector_type(4)));

__device__ __forceinline__ u16 f2bf(float x) {
    unsigned int u = __float_as_uint(x);
    unsigned int r = (u + 0x7fffu + ((u >> 16) & 1u)) >> 16;
    return (u16)r;
}

__device__ __forceinline__ bf16x8 ld_frag(const u16* p) {
    bf16x8 r;
    *reinterpret_cast<uint4*>(&r) = *reinterpret_cast<const uint4*>(p);
    return r;
}

__device__ __forceinline__ void gload_lds16(const u16* g, u16* l) {
    __builtin_amdgcn_global_load_lds((const __attribute__((address_space(1))) void*)g,
                                     (__attribute__((address_space(3))) void*)l, 16, 0, 0);
}

// ---------------- cast x fp32 -> bf16 ----------------
__global__ __launch_bounds__(256) void cast_f32_bf16(const float* __restrict__ in,
                                                     u16* __restrict__ out, int n4) {
    int i = blockIdx.x * 256 + threadIdx.x;
    if (i < n4) {
        float4 v = reinterpret_cast<const float4*>(in)[i];
        ushort4 o;
        o.x = f2bf(v.x); o.y = f2bf(v.y); o.z = f2bf(v.z); o.w = f2bf(v.w);
        reinterpret_cast<ushort4*>(out)[i] = o;
    }
}

// ---------------- transpose-cast W [K][N] fp32 -> [N][K] bf16 ----------------
__global__ __launch_bounds__(256) void transpose_cast(const float* __restrict__ in,
                                                      u16* __restrict__ out, int K, int N) {
    __shared__ u16 t[32][34];
    int k0 = blockIdx.x * 32, n0 = blockIdx.y * 32;
    for (int c = threadIdx.x; c < 1024; c += 256) {
        int k = c >> 5, n = c & 31;
        t[k][n] = f2bf(in[(size_t)(k0 + k) * N + n0 + n]);
    }
    __syncthreads();
    for (int c = threadIdx.x; c < 1024; c += 256) {
        int n = c >> 5, k = c & 31;
        out[(size_t)(n0 + n) * K + k0 + k] = t[k][n];
    }
}

// ---------------- GEMM: C[M,N] fp32 = A[M,K]bf16 @ Bt[N,K]bf16^T ----------------
__global__ __launch_bounds__(256) void gemm_bf16(const u16* __restrict__ A,
                                                 const u16* __restrict__ Bt,
                                                 float* __restrict__ C,
                                                 int M, int N, int K) {
    __shared__ u16 As[128 * 32];
    __shared__ u16 Bs[128 * 32];
    int tid = threadIdx.x;
    int lane = tid & 63, wave = tid >> 6;
    int quad = lane >> 4, l15 = lane & 15;
    int wr = wave >> 1, wc = wave & 1;
    int m0 = blockIdx.y * 128, n0 = blockIdx.x * 128;

    f32x4 zero = {0.f, 0.f, 0.f, 0.f};
    f32x4 acc[4][4];
    for (int i = 0; i < 4; i++)
        for (int j = 0; j < 4; j++) acc[i][j] = zero;

    int r0 = 16 * wave + (lane >> 2);
    int r1 = r0 + 64;
    int ks0 = (lane & 3) ^ ((r0 >> 1) & 3);
    int ks1 = (lane & 3) ^ ((r1 >> 1) & 3);
    const u16* ga0 = A + (size_t)(m0 + r0) * K + ks0 * 8;
    const u16* ga1 = A + (size_t)(m0 + r1) * K + ks1 * 8;
    const u16* gb0 = Bt + (size_t)(n0 + r0) * K + ks0 * 8;
    const u16* gb1 = Bt + (size_t)(n0 + r1) * K + ks1 * 8;
    u16* la0 = &As[wave * 512];
    u16* la1 = &As[(wave + 4) * 512];
    u16* lb0 = &Bs[wave * 512];
    u16* lb1 = &Bs[(wave + 4) * 512];

    int swz = (quad ^ ((l15 >> 1) & 3)) * 8;

    for (int k0 = 0; k0 < K; k0 += 32) {
        __syncthreads();
        gload_lds16(ga0 + k0, la0);
        gload_lds16(ga1 + k0, la1);
        gload_lds16(gb0 + k0, lb0);
        gload_lds16(gb1 + k0, lb1);
        __syncthreads();
        bf16x8 a[4], b[4];
        #pragma unroll
        for (int i = 0; i < 4; i++) a[i] = ld_frag(&As[(64 * wr + 16 * i + l15) * 32 + swz]);
        #pragma unroll
        for (int j = 0; j < 4; j++) b[j] = ld_frag(&Bs[(64 * wc + 16 * j + l15) * 32 + swz]);
        #pragma unroll
        for (int i = 0; i < 4; i++)
            #pragma unroll
            for (int j = 0; j < 4; j++)
                acc[i][j] = __builtin_amdgcn_mfma_f32_16x16x32_bf16(a[i], b[j], acc[i][j], 0, 0, 0);
    }
    for (int i = 0; i < 4; i++) {
        int rowb = m0 + 64 * wr + 16 * i + quad * 4;
        for (int j = 0; j < 4; j++) {
            int col = n0 + 64 * wc + 16 * j + l15;
            for (int r = 0; r < 4; r++)
                C[(size_t)(rowb + r) * N + col] = acc[i][j][r];
        }
    }
}

// ---------------- fused RMSNorm + RoPE, fp32 in -> bf16 head-major out ----------------
__global__ __launch_bounds__(256) void norm_rope(const float* __restrict__ raw,
                                                 const float* __restrict__ cosp,
                                                 const float* __restrict__ sinp,
                                                 const float* __restrict__ w,
                                                 u16* __restrict__ out,
                                                 int T, int nh, float outscale) {
    int wave = threadIdx.x >> 6, lane = threadIdx.x & 63;
    int wid = blockIdx.x * 4 + wave;
    int t = wid / nh, h = wid % nh;
    if (t >= T) return;
    const float* r = raw + (size_t)t * nh * 128 + h * 128;
    float v1 = r[lane], v2 = r[lane + 64];
    float ss = v1 * v1 + v2 * v2;
    for (int off = 1; off < 64; off <<= 1) ss += __shfl_xor(ss, off);
    float inv = rsqrtf(ss * (1.f / 128.f) + 1e-6f);
    float n1 = v1 * inv * w[lane], n2 = v2 * inv * w[lane + 64];
    float c = cosp[(size_t)t * 64 + lane], s = sinp[(size_t)t * 64 + lane];
    float o1 = (n1 * c - n2 * s) * outscale;
    float o2 = (n1 * s + n2 * c) * outscale;
    u16* op = out + ((size_t)h * T + t) * 128;
    op[lane] = f2bf(o1);
    op[lane + 64] = f2bf(o2);
}

// ---------------- V: [T][1024] fp32 -> [h][d][T] bf16 ----------------
__global__ __launch_bounds__(256) void v_transpose(const float* __restrict__ vraw,
                                                   u16* __restrict__ Vbt, int T) {
    __shared__ u16 tt[128][72];
    int h = blockIdx.y, t0 = blockIdx.x * 64;
    for (int c = threadIdx.x; c < 8192; c += 256) {
        int r = c >> 7, d = c & 127;
        tt[d][r] = f2bf(vraw[(size_t)(t0 + r) * HID + h * 128 + d]);
    }
    __syncthreads();
    for (int c = threadIdx.x; c < 8192; c += 256) {
        int d = c >> 6, r = c & 63;
        Vbt[((size_t)h * 128 + d) * T + t0 + r] = tt[d][r];
    }
}

// ---------------- causal MFMA flash attention, paired q-tiles, fully resident ----------------
// Block (h, j) processes qt = 63-j then qt = j: (64-j) + (j+1) = 65 iterations for
// EVERY block -> perfect balance. Grid = 16*32 = 512 blocks at 72 KB LDS = exactly
// 2 blocks/CU: whole grid co-resident, no dispatch tail, 8 waves/CU sustained.
// Double-buffered Ks/Vt with async global_load_lds issued before compute; one
// barrier per iteration. Row-sum via all-ones MFMA B-frag (lsum).
__global__ __launch_bounds__(256) void flash_attn(const u16* __restrict__ Qb,
                                                  const u16* __restrict__ Kb,
                                                  const u16* __restrict__ Vbt,
                                                  u16* __restrict__ attn, int T) {
    __shared__ u16 Ks[2][64 * 128];
    __shared__ u16 Vt[2][128 * 64];
    __shared__ u16 Ps[64 * 64];
    int tid = threadIdx.x;
    int lane = tid & 63, wave = tid >> 6;
    int quad = lane >> 4, l15 = lane & 15;
    int swb8 = (l15 & 7) * 8;  // row-XOR term: (s^x)*8 == s*8 ^ x*8
    int h = blockIdx.y;
    int j = (int)blockIdx.x;   // 0..31
    int kvh = h >> 1;

    const u16* kbase = Kb + (size_t)kvh * T * 128;
    const u16* vbase = Vbt + (size_t)kvh * 128 * T;

    int krow_ = (lane >> 4);
    int kseg_ = (lane & 15);
    int vrow_ = (lane >> 3);
    int vseg_ = (lane & 7);

    auto stage = [&](int s0, int b) {
        #pragma unroll
        for (int i = 0; i < 4; i++) {
            int ch = wave * 4 + i;
            int r = ch * 4 + krow_;
            int s = kseg_ ^ (r & 7);
            gload_lds16(kbase + (size_t)(s0 + r) * 128 + s * 8, &Ks[b][ch * 512]);
        }
        #pragma unroll
        for (int i = 0; i < 4; i++) {
            int ch = wave * 4 + i;
            int d = ch * 8 + vrow_;
            int s = vseg_ ^ (d & 7);
            gload_lds16(vbase + (size_t)d * T + s0 + s * 8, &Vt[b][ch * 512]);
        }
    };

    bf16x8 onesf;
    #pragma unroll
    for (int i = 0; i < 8; i++) onesf[i] = (__bf16)1.0f;
    f32x4 zero = {0.f, 0.f, 0.f, 0.f};

    for (int pass = 0; pass < 2; ++pass) {
        int qt = pass == 0 ? (63 - j) : j;
        int q0 = qt * 64;

        bf16x8 qf[4];
        {
            const u16* qp = Qb + ((size_t)h * T + q0 + 16 * wave + l15) * 128 + quad * 8;
            #pragma unroll
            for (int kk = 0; kk < 4; kk++) qf[kk] = ld_frag(qp + kk * 32);
        }

        float m_i[4];
        f32x4 lsum = zero;
        f32x4 o[8];
        for (int r = 0; r < 4; r++) m_i[r] = -3.0e38f;
        for (int dt = 0; dt < 8; dt++) o[dt] = zero;

        int ntiles = qt + 1;
        stage(0, 0);
        __syncthreads();  // vmcnt(0): tile 0 resident

        for (int it = 0; it < ntiles; ++it) {
            int b = it & 1;
            if (it + 1 < ntiles) stage((it + 1) * 64, 1 - b);  // async into other buffer
            int s0 = it * 64;

            f32x4 sc[4];
            for (int jt = 0; jt < 4; jt++) sc[jt] = zero;
            #pragma unroll
            for (int kk = 0; kk < 4; kk++)
                #pragma unroll
                for (int jt = 0; jt < 4; jt++) {
                    bf16x8 bfrag = ld_frag(&Ks[b][(jt * 16 + l15) * 128 + ((kk * 32 + quad * 8) ^ swb8)]);
                    sc[jt] = __builtin_amdgcn_mfma_f32_16x16x32_bf16(qf[kk], bfrag, sc[jt], 0, 0, 0);
                }

            if (s0 == q0) {  // diagonal tile: mask col > row
                #pragma unroll
                for (int jt = 0; jt < 4; jt++) {
                    int col = jt * 16 + l15;
                    for (int r = 0; r < 4; r++) {
                        int row = 16 * wave + quad * 4 + r;
                        if (col > row) sc[jt][r] = -1e30f;
                    }
                }
            }

            float alpha[4];
            #pragma unroll
            for (int r = 0; r < 4; r++) {
                float mt = fmaxf(fmaxf(sc[0][r], sc[1][r]), fmaxf(sc[2][r], sc[3][r]));
                for (int off = 1; off < 16; off <<= 1) mt = fmaxf(mt, __shfl_xor(mt, off));
                float mnew = fmaxf(m_i[r], mt);
                alpha[r] = __expf(m_i[r] - mnew);
                m_i[r] = mnew;
                for (int jt = 0; jt < 4; jt++)
                    sc[jt][r] = __expf(sc[jt][r] - mnew);
            }

            #pragma unroll
            for (int jt = 0; jt < 4; jt++)
                for (int r = 0; r < 4; r++) {
                    int pr = 16 * wave + quad * 4 + r;
                    int cb = jt * 16 + l15;
                    Ps[pr * 64 + ((((cb >> 3) ^ (pr & 7)) << 3) | (cb & 7))] = f2bf(sc[jt][r]);
                }

            // rescale while the ds_writes drain (independent of Ps)
            #pragma unroll
            for (int r = 0; r < 4; r++) lsum[r] *= alpha[r];
            #pragma unroll
            for (int dt = 0; dt < 8; dt++)
                for (int r = 0; r < 4; r++) o[dt][r] *= alpha[r];

            asm volatile("s_waitcnt lgkmcnt(0)" ::: "memory");  // wave-private Ps ordering

            #pragma unroll
            for (int kk2 = 0; kk2 < 2; kk2++) {
                bf16x8 pa = ld_frag(&Ps[(16 * wave + l15) * 64 + ((kk2 * 32 + quad * 8) ^ swb8)]);
                lsum = __builtin_amdgcn_mfma_f32_16x16x32_bf16(pa, onesf, lsum, 0, 0, 0);
                #pragma unroll
                for (int dt = 0; dt < 8; dt++) {
                    bf16x8 vb = ld_frag(&Vt[b][(dt * 16 + l15) * 64 + ((kk2 * 32 + quad * 8) ^ swb8)]);
                    o[dt] = __builtin_amdgcn_mfma_f32_16x16x32_bf16(pa, vb, o[dt], 0, 0, 0);
                }
            }
            __syncthreads();  // drains next-tile loads (post-compute) + buffer handoff
        }

        float inv[4];
        for (int r = 0; r < 4; r++) inv[r] = 1.f / lsum[r];
        for (int dt = 0; dt < 8; dt++)
            for (int r = 0; r < 4; r++) {
                int row = q0 + 16 * wave + quad * 4 + r;
                attn[(size_t)row * NQ + h * DHEAD + dt * 16 + l15] = f2bf(o[dt][r] * inv[r]);
            }
    }
}

extern "C" void kernel_launch(void* const* d_in, const int* in_sizes, int n_in,
                              void* d_out, int out_size, void* d_ws, size_t ws_size,
                              hipStream_t stream) {
    const float* x    = (const float*)d_in[0];
    const float* cosp = (const float*)d_in[1];
    const float* sinp = (const float*)d_in[2];
    const float* Wq   = (const float*)d_in[3];
    const float* Wk   = (const float*)d_in[4];
    const float* Wv   = (const float*)d_in[5];
    const float* Wo   = (const float*)d_in[6];
    const float* qnw  = (const float*)d_in[7];
    const float* knw  = (const float*)d_in[8];
    float* out = (float*)d_out;
    const int T = in_sizes[1] / 64;  // 4096

    char* ws = (char*)d_ws;
    size_t off = 0;
    auto alloc = [&](size_t bytes) {
        char* p = ws + off;
        off += (bytes + 255) & ~(size_t)255;
        return p;
    };
    u16*   xb   = (u16*)alloc((size_t)T * HID * 2);
    u16*   Wqb  = (u16*)alloc((size_t)NQ * HID * 2);
    u16*   Wkb  = (u16*)alloc((size_t)HID * HID * 2);
    u16*   Wvb  = (u16*)alloc((size_t)HID * HID * 2);
    u16*   Wob  = (u16*)alloc((size_t)HID * NQ * 2);
    float* qraw = (float*)alloc((size_t)T * NQ * 4);
    float* kraw = (float*)alloc((size_t)T * HID * 4);
    float* vraw = (float*)alloc((size_t)T * HID * 4);
    u16*   Qb   = (u16*)alloc((size_t)H2 * T * DHEAD * 2);
    u16*   Kb   = (u16*)alloc((size_t)HKV * T * DHEAD * 2);
    u16*   Vbt  = (u16*)alloc((size_t)HKV * DHEAD * T * 2);
    u16*   attn = (u16*)alloc((size_t)T * NQ * 2);

    cast_f32_bf16<<<(T * HID / 4 + 255) / 256, 256, 0, stream>>>(x, xb, T * HID / 4);
    transpose_cast<<<dim3(HID / 32, NQ / 32), 256, 0, stream>>>(Wq, Wqb, HID, NQ);
    transpose_cast<<<dim3(HID / 32, HID / 32), 256, 0, stream>>>(Wk, Wkb, HID, HID);
    transpose_cast<<<dim3(HID / 32, HID / 32), 256, 0, stream>>>(Wv, Wvb, HID, HID);
    transpose_cast<<<dim3(NQ / 32, HID / 32), 256, 0, stream>>>(Wo, Wob, NQ, HID);

    gemm_bf16<<<dim3(NQ / 128, T / 128), 256, 0, stream>>>(xb, Wqb, qraw, T, NQ, HID);
    gemm_bf16<<<dim3(HID / 128, T / 128), 256, 0, stream>>>(xb, Wkb, kraw, T, HID, HID);
    gemm_bf16<<<dim3(HID / 128, T / 128), 256, 0, stream>>>(xb, Wvb, vraw, T, HID, HID);

    const float scale = 0.08838834764831845f;  // 128^-0.5 folded into Q
    norm_rope<<<T * H2 / 4, 256, 0, stream>>>(qraw, cosp, sinp, qnw, Qb, T, H2, scale);
    norm_rope<<<T * HKV / 4, 256, 0, stream>>>(kraw, cosp, sinp, knw, Kb, T, HKV, 1.0f);
    v_transpose<<<dim3(T / 64, HKV), 256, 0, stream>>>(vraw, Vbt, T);

    flash_attn<<<dim3(32, H2), 256, 0, stream>>>(Qb, Kb, Vbt, attn, T);

    gemm_bf16<<<dim3(HID / 128, T / 128), 256, 0, stream>>>(attn, Wob, out, T, HID, NQ);
}

// Round 7
// 377.453 us; speedup vs baseline: 1.9161x; 1.1338x over previous
//
#include <hip/hip_runtime.h>
#include <hip/hip_bf16.h>

#define H2 16
#define HKV 8
#define DHEAD 128
#define HID 1024
#define NQ 2048

typedef unsigned short u16;
typedef __bf16 bf16x8 __attribute__((ext_vector_type(8)));
typedef float f32x4 __attribute__((ext_vector_type(4)));

__device__ __forceinline__ u16 f2bf(float x) {
    unsigned int u = __float_as_uint(x);
    unsigned int r = (u + 0x7fffu + ((u >> 16) & 1u)) >> 16;
    return (u16)r;
}

// pack two fp32 -> (bf16(hi)<<16)|bf16(lo), round-half-up via +0x8000 then v_perm
__device__ __forceinline__ unsigned int pack_bf16(float hi, float lo) {
    unsigned int a = __float_as_uint(hi) + 0x8000u;
    unsigned int b = __float_as_uint(lo) + 0x8000u;
    return __builtin_amdgcn_perm(a, b, 0x07060302u);
}

__device__ __forceinline__ bf16x8 ld_frag(const u16* p) {
    bf16x8 r;
    *reinterpret_cast<uint4*>(&r) = *reinterpret_cast<const uint4*>(p);
    return r;
}

__device__ __forceinline__ void gload_lds16(const u16* g, u16* l) {
    __builtin_amdgcn_global_load_lds((const __attribute__((address_space(1))) void*)g,
                                     (__attribute__((address_space(3))) void*)l, 16, 0, 0);
}

// ---------------- cast x fp32 -> bf16 ----------------
__global__ __launch_bounds__(256) void cast_f32_bf16(const float* __restrict__ in,
                                                     u16* __restrict__ out, int n4) {
    int i = blockIdx.x * 256 + threadIdx.x;
    if (i < n4) {
        float4 v = reinterpret_cast<const float4*>(in)[i];
        ushort4 o;
        o.x = f2bf(v.x); o.y = f2bf(v.y); o.z = f2bf(v.z); o.w = f2bf(v.w);
        reinterpret_cast<ushort4*>(out)[i] = o;
    }
}

// ---------------- transpose-cast W [K][N] fp32 -> [N][K] bf16 ----------------
__global__ __launch_bounds__(256) void transpose_cast(const float* __restrict__ in,
                                                      u16* __restrict__ out, int K, int N) {
    __shared__ u16 t[32][34];
    int k0 = blockIdx.x * 32, n0 = blockIdx.y * 32;
    for (int c = threadIdx.x; c < 1024; c += 256) {
        int k = c >> 5, n = c & 31;
        t[k][n] = f2bf(in[(size_t)(k0 + k) * N + n0 + n]);
    }
    __syncthreads();
    for (int c = threadIdx.x; c < 1024; c += 256) {
        int n = c >> 5, k = c & 31;
        out[(size_t)(n0 + n) * K + k0 + k] = t[k][n];
    }
}

// ---------------- GEMM: C[M,N] fp32 = A[M,K]bf16 @ Bt[N,K]bf16^T ----------------
__global__ __launch_bounds__(256) void gemm_bf16(const u16* __restrict__ A,
                                                 const u16* __restrict__ Bt,
                                                 float* __restrict__ C,
                                                 int M, int N, int K) {
    __shared__ u16 As[128 * 32];
    __shared__ u16 Bs[128 * 32];
    int tid = threadIdx.x;
    int lane = tid & 63, wave = tid >> 6;
    int quad = lane >> 4, l15 = lane & 15;
    int wr = wave >> 1, wc = wave & 1;
    int m0 = blockIdx.y * 128, n0 = blockIdx.x * 128;

    f32x4 zero = {0.f, 0.f, 0.f, 0.f};
    f32x4 acc[4][4];
    for (int i = 0; i < 4; i++)
        for (int j = 0; j < 4; j++) acc[i][j] = zero;

    int r0 = 16 * wave + (lane >> 2);
    int r1 = r0 + 64;
    int ks0 = (lane & 3) ^ ((r0 >> 1) & 3);
    int ks1 = (lane & 3) ^ ((r1 >> 1) & 3);
    const u16* ga0 = A + (size_t)(m0 + r0) * K + ks0 * 8;
    const u16* ga1 = A + (size_t)(m0 + r1) * K + ks1 * 8;
    const u16* gb0 = Bt + (size_t)(n0 + r0) * K + ks0 * 8;
    const u16* gb1 = Bt + (size_t)(n0 + r1) * K + ks1 * 8;
    u16* la0 = &As[wave * 512];
    u16* la1 = &As[(wave + 4) * 512];
    u16* lb0 = &Bs[wave * 512];
    u16* lb1 = &Bs[(wave + 4) * 512];

    int swz = (quad ^ ((l15 >> 1) & 3)) * 8;

    for (int k0 = 0; k0 < K; k0 += 32) {
        __syncthreads();
        gload_lds16(ga0 + k0, la0);
        gload_lds16(ga1 + k0, la1);
        gload_lds16(gb0 + k0, lb0);
        gload_lds16(gb1 + k0, lb1);
        __syncthreads();
        bf16x8 a[4], b[4];
        #pragma unroll
        for (int i = 0; i < 4; i++) a[i] = ld_frag(&As[(64 * wr + 16 * i + l15) * 32 + swz]);
        #pragma unroll
        for (int j = 0; j < 4; j++) b[j] = ld_frag(&Bs[(64 * wc + 16 * j + l15) * 32 + swz]);
        #pragma unroll
        for (int i = 0; i < 4; i++)
            #pragma unroll
            for (int j = 0; j < 4; j++)
                acc[i][j] = __builtin_amdgcn_mfma_f32_16x16x32_bf16(a[i], b[j], acc[i][j], 0, 0, 0);
    }
    for (int i = 0; i < 4; i++) {
        int rowb = m0 + 64 * wr + 16 * i + quad * 4;
        for (int j = 0; j < 4; j++) {
            int col = n0 + 64 * wc + 16 * j + l15;
            for (int r = 0; r < 4; r++)
                C[(size_t)(rowb + r) * N + col] = acc[i][j][r];
        }
    }
}

// ---------------- fused RMSNorm + RoPE, fp32 in (strided) -> bf16 head-major out ----------------
__global__ __launch_bounds__(256) void norm_rope(const float* __restrict__ raw,
                                                 const float* __restrict__ cosp,
                                                 const float* __restrict__ sinp,
                                                 const float* __restrict__ w,
                                                 u16* __restrict__ out,
                                                 int T, int nh, int rowstride, int coloff,
                                                 float outscale) {
    int wave = threadIdx.x >> 6, lane = threadIdx.x & 63;
    int wid = blockIdx.x * 4 + wave;
    int t = wid / nh, h = wid % nh;
    if (t >= T) return;
    const float* r = raw + (size_t)t * rowstride + coloff + h * 128;
    float v1 = r[lane], v2 = r[lane + 64];
    float ss = v1 * v1 + v2 * v2;
    for (int off = 1; off < 64; off <<= 1) ss += __shfl_xor(ss, off);
    float inv = rsqrtf(ss * (1.f / 128.f) + 1e-6f);
    float n1 = v1 * inv * w[lane], n2 = v2 * inv * w[lane + 64];
    float c = cosp[(size_t)t * 64 + lane], s = sinp[(size_t)t * 64 + lane];
    float o1 = (n1 * c - n2 * s) * outscale;
    float o2 = (n1 * s + n2 * c) * outscale;
    u16* op = out + ((size_t)h * T + t) * 128;
    op[lane] = f2bf(o1);
    op[lane + 64] = f2bf(o2);
}

// ---------------- V: qkvraw[T][4096] (cols 3072..4095) fp32 -> [h][d][T] bf16 ----------------
__global__ __launch_bounds__(256) void v_transpose(const float* __restrict__ vraw,
                                                   u16* __restrict__ Vbt, int T) {
    __shared__ u16 tt[128][72];
    int h = blockIdx.y, t0 = blockIdx.x * 64;
    for (int c = threadIdx.x; c < 8192; c += 256) {
        int r = c >> 7, d = c & 127;
        tt[d][r] = f2bf(vraw[(size_t)(t0 + r) * 4096 + 3072 + h * 128 + d]);
    }
    __syncthreads();
    for (int c = threadIdx.x; c < 8192; c += 256) {
        int d = c >> 6, r = c & 63;
        Vbt[((size_t)h * 128 + d) * T + t0 + r] = tt[d][r];
    }
}

// ---------------- causal MFMA flash attention, S^T softmax, paired q-tiles ----------------
// Block (h, j): qt = 63-j then qt = j -> 65 iterations every block; 512 blocks at
// 72 KB LDS = whole grid co-resident (2 blocks/CU). Double-buffered async K/V.
// QK computed TRANSPOSED (A=K, B=Q): each lane owns ONE q-row (its l15) with 16
// s-scores -> max butterfly is 2 shuffles, one m/alpha per lane, and P^T rows
// are contiguous in s -> 4 packed ds_write_b64 (v_perm bf16 pack) instead of 16
// scalar writes. Ps swizzled in 16B blocks so PV A-frag stays one ds_read_b128.
__global__ __launch_bounds__(256) void flash_attn(const u16* __restrict__ Qb,
                                                  const u16* __restrict__ Kb,
                                                  const u16* __restrict__ Vbt,
                                                  u16* __restrict__ attn, int T) {
    __shared__ u16 Ks[2][64 * 128];
    __shared__ u16 Vt[2][128 * 64];
    __shared__ u16 Ps[64 * 64];
    int tid = threadIdx.x;
    int lane = tid & 63, wave = tid >> 6;
    int quad = lane >> 4, l15 = lane & 15;
    int swb8 = (l15 & 7) * 8;  // row-XOR term: (s^x)*8 == s*8 ^ x*8
    int h = blockIdx.y;
    int j = (int)blockIdx.x;   // 0..31
    int kvh = h >> 1;

    const u16* kbase = Kb + (size_t)kvh * T * 128;
    const u16* vbase = Vbt + (size_t)kvh * 128 * T;

    int krow_ = (lane >> 4);
    int kseg_ = (lane & 15);
    int vrow_ = (lane >> 3);
    int vseg_ = (lane & 7);

    auto stage = [&](int s0, int b) {
        #pragma unroll
        for (int i = 0; i < 4; i++) {
            int ch = wave * 4 + i;
            int r = ch * 4 + krow_;
            int s = kseg_ ^ (r & 7);
            gload_lds16(kbase + (size_t)(s0 + r) * 128 + s * 8, &Ks[b][ch * 512]);
        }
        #pragma unroll
        for (int i = 0; i < 4; i++) {
            int ch = wave * 4 + i;
            int d = ch * 8 + vrow_;
            int s = vseg_ ^ (d & 7);
            gload_lds16(vbase + (size_t)d * T + s0 + s * 8, &Vt[b][ch * 512]);
        }
    };

    bf16x8 onesf;
    #pragma unroll
    for (int i = 0; i < 8; i++) onesf[i] = (__bf16)1.0f;
    f32x4 zero = {0.f, 0.f, 0.f, 0.f};
    const float L2E = 1.44269504f;

    for (int pass = 0; pass < 2; ++pass) {
        int qt = pass == 0 ? (63 - j) : j;
        int q0 = qt * 64;

        bf16x8 qf[4];
        {
            const u16* qp = Qb + ((size_t)h * T + q0 + 16 * wave + l15) * 128 + quad * 8;
            #pragma unroll
            for (int kk = 0; kk < 4; kk++) qf[kk] = ld_frag(qp + kk * 32);
        }

        float m_i = -3.0e38f;       // per-lane: q-row = 16*wave + l15
        f32x4 lsum = zero;          // C-layout rows: q = 16*wave + quad*4 + r
        f32x4 o[8];
        for (int dt = 0; dt < 8; dt++) o[dt] = zero;

        int ntiles = qt + 1;
        stage(0, 0);
        __syncthreads();  // vmcnt(0): tile 0 resident

        for (int it = 0; it < ntiles; ++it) {
            int b = it & 1;
            if (it + 1 < ntiles) stage((it + 1) * 64, 1 - b);  // async into other buffer
            int s0 = it * 64;

            // S^T: A=K (m->s), B=Q (n->q). scT[jt][r]: s = jt*16+quad*4+r, q = 16*wave+l15
            f32x4 scT[4];
            for (int jt = 0; jt < 4; jt++) scT[jt] = zero;
            #pragma unroll
            for (int kk = 0; kk < 4; kk++)
                #pragma unroll
                for (int jt = 0; jt < 4; jt++) {
                    bf16x8 kfrag = ld_frag(&Ks[b][(jt * 16 + l15) * 128 + ((kk * 32 + quad * 8) ^ swb8)]);
                    scT[jt] = __builtin_amdgcn_mfma_f32_16x16x32_bf16(kfrag, qf[kk], scT[jt], 0, 0, 0);
                }

            if (s0 == q0) {  // diagonal tile: mask s > q
                int qloc = 16 * wave + l15;
                #pragma unroll
                for (int jt = 0; jt < 4; jt++)
                    for (int r = 0; r < 4; r++)
                        if (jt * 16 + quad * 4 + r > qloc) scT[jt][r] = -1e30f;
            }

            // lane-local max over 16 scores (same q), then 2-step quad butterfly
            float mt = scT[0][0];
            #pragma unroll
            for (int jt = 0; jt < 4; jt++)
                for (int r = 0; r < 4; r++) mt = fmaxf(mt, scT[jt][r]);
            mt = fmaxf(mt, __shfl_xor(mt, 16));
            mt = fmaxf(mt, __shfl_xor(mt, 32));
            float mnew = fmaxf(m_i, mt);
            float alpha = __expf(m_i - mnew);
            m_i = mnew;
            float mls = mnew * L2E;

            #pragma unroll
            for (int jt = 0; jt < 4; jt++)
                for (int r = 0; r < 4; r++)
                    scT[jt][r] = exp2f(fmaf(scT[jt][r], L2E, -mls));

            // P^T -> Ps[q][s]: 4 consecutive s per (jt) -> one packed b64 write
            {
                int prow = 16 * wave + l15;
                #pragma unroll
                for (int jt = 0; jt < 4; jt++) {
                    int s8 = 2 * jt + (quad >> 1);
                    uint2 wv;
                    wv.x = pack_bf16(scT[jt][1], scT[jt][0]);
                    wv.y = pack_bf16(scT[jt][3], scT[jt][2]);
                    *reinterpret_cast<uint2*>(&Ps[prow * 64 + (s8 ^ (l15 & 7)) * 8 + (quad & 1) * 4]) = wv;
                }
            }

            // broadcast alpha to o-rescale rows (q = 16*wave + quad*4 + r)
            float av[4];
            #pragma unroll
            for (int r = 0; r < 4; r++) av[r] = __shfl(alpha, quad * 4 + r);
            #pragma unroll
            for (int r = 0; r < 4; r++) lsum[r] *= av[r];
            #pragma unroll
            for (int dt = 0; dt < 8; dt++)
                for (int r = 0; r < 4; r++) o[dt][r] *= av[r];

            asm volatile("s_waitcnt lgkmcnt(0)" ::: "memory");  // wave-private Ps ordering

            #pragma unroll
            for (int kk2 = 0; kk2 < 2; kk2++) {
                bf16x8 pa = ld_frag(&Ps[(16 * wave + l15) * 64 + (((4 * kk2 + quad) ^ (l15 & 7)) * 8)]);
                lsum = __builtin_amdgcn_mfma_f32_16x16x32_bf16(pa, onesf, lsum, 0, 0, 0);
                #pragma unroll
                for (int dt = 0; dt < 8; dt++) {
                    bf16x8 vb = ld_frag(&Vt[b][(dt * 16 + l15) * 64 + ((kk2 * 32 + quad * 8) ^ swb8)]);
                    o[dt] = __builtin_amdgcn_mfma_f32_16x16x32_bf16(pa, vb, o[dt], 0, 0, 0);
                }
            }
            __syncthreads();  // drains next-tile loads (post-compute) + buffer handoff
        }

        float inv[4];
        for (int r = 0; r < 4; r++) inv[r] = 1.f / lsum[r];
        for (int dt = 0; dt < 8; dt++)
            for (int r = 0; r < 4; r++) {
                int row = q0 + 16 * wave + quad * 4 + r;
                attn[(size_t)row * NQ + h * DHEAD + dt * 16 + l15] = f2bf(o[dt][r] * inv[r]);
            }
    }
}

extern "C" void kernel_launch(void* const* d_in, const int* in_sizes, int n_in,
                              void* d_out, int out_size, void* d_ws, size_t ws_size,
                              hipStream_t stream) {
    const float* x    = (const float*)d_in[0];
    const float* cosp = (const float*)d_in[1];
    const float* sinp = (const float*)d_in[2];
    const float* Wq   = (const float*)d_in[3];
    const float* Wk   = (const float*)d_in[4];
    const float* Wv   = (const float*)d_in[5];
    const float* Wo   = (const float*)d_in[6];
    const float* qnw  = (const float*)d_in[7];
    const float* knw  = (const float*)d_in[8];
    float* out = (float*)d_out;
    const int T = in_sizes[1] / 64;  // 4096

    char* ws = (char*)d_ws;
    size_t off = 0;
    auto alloc = [&](size_t bytes) {
        char* p = ws + off;
        off += (bytes + 255) & ~(size_t)255;
        return p;
    };
    u16*   xb     = (u16*)alloc((size_t)T * HID * 2);
    u16*   Wqkvb  = (u16*)alloc((size_t)4096 * HID * 2);  // rows: q 0..2047, k 2048..3071, v 3072..4095
    u16*   Wob    = (u16*)alloc((size_t)HID * NQ * 2);
    float* qkvraw = (float*)alloc((size_t)T * 4096 * 4);
    u16*   Qb     = (u16*)alloc((size_t)H2 * T * DHEAD * 2);
    u16*   Kb     = (u16*)alloc((size_t)HKV * T * DHEAD * 2);
    u16*   Vbt    = (u16*)alloc((size_t)HKV * DHEAD * T * 2);
    u16*   attn   = (u16*)alloc((size_t)T * NQ * 2);

    cast_f32_bf16<<<(T * HID / 4 + 255) / 256, 256, 0, stream>>>(x, xb, T * HID / 4);
    transpose_cast<<<dim3(HID / 32, NQ / 32), 256, 0, stream>>>(Wq, Wqkvb, HID, NQ);
    transpose_cast<<<dim3(HID / 32, HID / 32), 256, 0, stream>>>(Wk, Wqkvb + (size_t)2048 * HID, HID, HID);
    transpose_cast<<<dim3(HID / 32, HID / 32), 256, 0, stream>>>(Wv, Wqkvb + (size_t)3072 * HID, HID, HID);
    transpose_cast<<<dim3(NQ / 32, HID / 32), 256, 0, stream>>>(Wo, Wob, NQ, HID);

    // fused QKV: C[T][4096]
    gemm_bf16<<<dim3(4096 / 128, T / 128), 256, 0, stream>>>(xb, Wqkvb, qkvraw, T, 4096, HID);

    const float scale = 0.08838834764831845f;  // 128^-0.5 folded into Q
    norm_rope<<<T * H2 / 4, 256, 0, stream>>>(qkvraw, cosp, sinp, qnw, Qb, T, H2, 4096, 0, scale);
    norm_rope<<<T * HKV / 4, 256, 0, stream>>>(qkvraw, cosp, sinp, knw, Kb, T, HKV, 4096, 2048, 1.0f);
    v_transpose<<<dim3(T / 64, HKV), 256, 0, stream>>>(qkvraw, Vbt, T);

    flash_attn<<<dim3(32, H2), 256, 0, stream>>>(Qb, Kb, Vbt, attn, T);

    gemm_bf16<<<dim3(HID / 128, T / 128), 256, 0, stream>>>(attn, Wob, out, T, HID, NQ);
}